// Round 1
// baseline (864.824 us; speedup 1.0000x reference)
//
#include <hip/hip_runtime.h>
#include <hip/hip_bf16.h>
#include <math.h>

// Problem constants
#define B_SZ    8
#define T_LEN   4096
#define DIN     256
#define DOUT    256
#define NST     512
#define M_ROWS  (B_SZ * T_LEN)   // 32768
#define N1      (2 * NST)        // 1024: Bu real plane cols [0,512), imag [512,1024)
#define K2      (N1 + DIN)       // 1280: x_r | x_i | u concatenated K for output GEMM

// ws layout (in floats):
//   [0, M_ROWS*N1)          Bu, later x (in-place scan)   = 134 MB
//   off1: Wp  [N1][DIN]     gamma-folded B_real|B_imag    = 1 MB
//   off2: W2  [DOUT][K2]    2*C_real | -2*C_imag | D      = 1.25 MB
//   off3: lam [2*NST]       lam_r | lam_i
static const size_t OFF1 = (size_t)M_ROWS * N1;          // 33554432
static const size_t OFF2 = OFF1 + (size_t)N1 * DIN;      // +262144
static const size_t OFF3 = OFF2 + (size_t)DOUT * K2;     // +327680

// ---- pack W1 (gamma * B) and lambda ----
__global__ void pack_w1(const float* __restrict__ nu_log,
                        const float* __restrict__ theta_log,
                        const float* __restrict__ gamma_log,
                        const float* __restrict__ B_real,
                        const float* __restrict__ B_imag,
                        float* __restrict__ Wp, float* __restrict__ lam) {
    int c = blockIdx.x;          // 0..1023
    int k = threadIdx.x;         // 0..255
    int n = c & (NST - 1);
    float g = expf(gamma_log[n]);
    const float* src = (c < NST) ? (B_real + (size_t)n * DIN)
                                 : (B_imag + (size_t)n * DIN);
    Wp[(size_t)c * DIN + k] = g * src[k];
    int idx = c * 256 + k;
    if (idx < NST) {
        float lm = expf(-expf(nu_log[idx]));
        float th = expf(theta_log[idx]);
        lam[idx]        = lm * cosf(th);
        lam[NST + idx]  = lm * sinf(th);
    }
}

// ---- pack W2: [DOUT][K2] = 2*C_real | -2*C_imag | D ----
__global__ void pack_w2(const float* __restrict__ C_real,
                        const float* __restrict__ C_imag,
                        const float* __restrict__ Dm,
                        float* __restrict__ W2) {
    int idx = blockIdx.x * 256 + threadIdx.x;
    if (idx >= DOUT * K2) return;
    int o = idx / K2;
    int c = idx - o * K2;
    float v;
    if (c < NST)            v =  2.0f * C_real[(size_t)o * NST + c];
    else if (c < 2 * NST)   v = -2.0f * C_imag[(size_t)o * NST + (c - NST)];
    else                    v =  Dm[(size_t)o * DIN + (c - 2 * NST)];
    W2[idx] = v;
}

// ---- GEMM 1: Bu[M][N1] = u[M][DIN] * Wp[N1][DIN]^T ----
// 64x64 tile, BK=16, 256 threads, 4x4 microtile
__global__ __launch_bounds__(256) void gemm_bu(const float* __restrict__ u,
                                               const float* __restrict__ Wp,
                                               float* __restrict__ Bu) {
    __shared__ __align__(16) float As[16][68];
    __shared__ __align__(16) float Ws[16][68];
    int m0 = blockIdx.x * 64, n0 = blockIdx.y * 64;
    int tid = threadIdx.x;
    int lr = tid >> 2;              // 0..63
    int lk = (tid & 3) * 4;         // 0,4,8,12
    int tm = (tid >> 4) * 4;        // 0..60
    int tn = (tid & 15) * 4;        // 0..60
    float acc[4][4] = {};
    for (int k0 = 0; k0 < DIN; k0 += 16) {
        float4 av = *(const float4*)(u  + (size_t)(m0 + lr) * DIN + k0 + lk);
        float4 wv = *(const float4*)(Wp + (size_t)(n0 + lr) * DIN + k0 + lk);
        As[lk + 0][lr] = av.x; As[lk + 1][lr] = av.y;
        As[lk + 2][lr] = av.z; As[lk + 3][lr] = av.w;
        Ws[lk + 0][lr] = wv.x; Ws[lk + 1][lr] = wv.y;
        Ws[lk + 2][lr] = wv.z; Ws[lk + 3][lr] = wv.w;
        __syncthreads();
#pragma unroll
        for (int kk = 0; kk < 16; ++kk) {
            float4 a = *(const float4*)(&As[kk][tm]);
            float4 w = *(const float4*)(&Ws[kk][tn]);
            float ar[4] = {a.x, a.y, a.z, a.w};
            float wr[4] = {w.x, w.y, w.z, w.w};
#pragma unroll
            for (int i = 0; i < 4; ++i)
#pragma unroll
                for (int j = 0; j < 4; ++j)
                    acc[i][j] += ar[i] * wr[j];
        }
        __syncthreads();
    }
#pragma unroll
    for (int i = 0; i < 4; ++i) {
        float4 v = make_float4(acc[i][0], acc[i][1], acc[i][2], acc[i][3]);
        *(float4*)(Bu + (size_t)(m0 + tm + i) * N1 + n0 + tn) = v;
    }
}

// ---- scan: x_t = lam * x_{t-1} + Bu_t, in-place over Bu ----
__global__ __launch_bounds__(256) void scan_kernel(float* __restrict__ Bu,
                                                   const float* __restrict__ lam) {
    int idx = blockIdx.x * 256 + threadIdx.x;   // 0..4095
    int b = idx >> 9;
    int n = idx & (NST - 1);
    float lr = lam[n], li = lam[NST + n];
    float xr = 0.f, xi = 0.f;
    float* pr = Bu + (size_t)b * T_LEN * N1 + n;
    float* pi = pr + NST;
    for (int t = 0; t < T_LEN; ++t) {
        size_t off = (size_t)t * N1;
        float br = pr[off], bi = pi[off];
        float nr = lr * xr - li * xi + br;
        float ni = lr * xi + li * xr + bi;
        xr = nr; xi = ni;
        pr[off] = xr; pi[off] = xi;
    }
}

// ---- GEMM 2: y[M][DOUT] = Acat[M][K2] * W2[DOUT][K2]^T ----
// Acat cols [0,1024) from Bu (lda N1), [1024,1280) from u (lda DIN)
__global__ __launch_bounds__(256) void gemm_y(const float* __restrict__ Bu,
                                              const float* __restrict__ u,
                                              const float* __restrict__ W2,
                                              float* __restrict__ y) {
    __shared__ __align__(16) float As[16][68];
    __shared__ __align__(16) float Ws[16][68];
    int m0 = blockIdx.x * 64, n0 = blockIdx.y * 64;
    int tid = threadIdx.x;
    int lr = tid >> 2;
    int lk = (tid & 3) * 4;
    int tm = (tid >> 4) * 4;
    int tn = (tid & 15) * 4;
    float acc[4][4] = {};
    for (int k0 = 0; k0 < K2; k0 += 16) {
        const float* Aptr; int lda, kc;
        if (k0 < N1) { Aptr = Bu; lda = N1;  kc = k0; }
        else         { Aptr = u;  lda = DIN; kc = k0 - N1; }
        float4 av = *(const float4*)(Aptr + (size_t)(m0 + lr) * lda + kc + lk);
        float4 wv = *(const float4*)(W2 + (size_t)(n0 + lr) * K2 + k0 + lk);
        As[lk + 0][lr] = av.x; As[lk + 1][lr] = av.y;
        As[lk + 2][lr] = av.z; As[lk + 3][lr] = av.w;
        Ws[lk + 0][lr] = wv.x; Ws[lk + 1][lr] = wv.y;
        Ws[lk + 2][lr] = wv.z; Ws[lk + 3][lr] = wv.w;
        __syncthreads();
#pragma unroll
        for (int kk = 0; kk < 16; ++kk) {
            float4 a = *(const float4*)(&As[kk][tm]);
            float4 w = *(const float4*)(&Ws[kk][tn]);
            float ar[4] = {a.x, a.y, a.z, a.w};
            float wr[4] = {w.x, w.y, w.z, w.w};
#pragma unroll
            for (int i = 0; i < 4; ++i)
#pragma unroll
                for (int j = 0; j < 4; ++j)
                    acc[i][j] += ar[i] * wr[j];
        }
        __syncthreads();
    }
#pragma unroll
    for (int i = 0; i < 4; ++i) {
        float4 v = make_float4(acc[i][0], acc[i][1], acc[i][2], acc[i][3]);
        *(float4*)(y + (size_t)(m0 + tm + i) * DOUT + n0 + tn) = v;
    }
}

extern "C" void kernel_launch(void* const* d_in, const int* in_sizes, int n_in,
                              void* d_out, int out_size, void* d_ws, size_t ws_size,
                              hipStream_t stream) {
    const float* u_in      = (const float*)d_in[0];
    const float* nu_log    = (const float*)d_in[1];
    const float* theta_log = (const float*)d_in[2];
    const float* gamma_log = (const float*)d_in[3];
    const float* B_real    = (const float*)d_in[4];
    const float* B_imag    = (const float*)d_in[5];
    const float* C_real    = (const float*)d_in[6];
    const float* C_imag    = (const float*)d_in[7];
    const float* Dm        = (const float*)d_in[8];
    float* y  = (float*)d_out;
    float* ws = (float*)d_ws;

    float* Bu  = ws;
    float* Wp  = ws + OFF1;
    float* W2  = ws + OFF2;
    float* lam = ws + OFF3;

    pack_w1<<<N1, 256, 0, stream>>>(nu_log, theta_log, gamma_log, B_real, B_imag, Wp, lam);
    pack_w2<<<(DOUT * K2 + 255) / 256, 256, 0, stream>>>(C_real, C_imag, Dm, W2);
    gemm_bu<<<dim3(M_ROWS / 64, N1 / 64), 256, 0, stream>>>(u_in, Wp, Bu);
    scan_kernel<<<(B_SZ * NST) / 256, 256, 0, stream>>>(Bu, lam);
    gemm_y<<<dim3(M_ROWS / 64, DOUT / 64), 256, 0, stream>>>(Bu, u_in, W2, y);
}

// Round 2
// 212.173 us; speedup vs baseline: 4.0760x; 4.0760x over previous
//
#include <hip/hip_runtime.h>
#include <hip/hip_bf16.h>
#include <math.h>

#define B_SZ    8
#define T_LEN   4096
#define DIN     256
#define DOUT    256
#define NST     512
#define M_ROWS  (B_SZ * T_LEN)   // 32768
#define N1      (2 * NST)        // 1024
#define K2      (N1 + DIN)       // 1280
#define CHL     128              // scan chunk length
#define NCH     (T_LEN / CHL)    // 32

typedef __attribute__((ext_vector_type(8))) short bf16x8;
typedef __attribute__((ext_vector_type(4))) float f32x4;
typedef __hip_bfloat16 bf16;

// ---- ws byte offsets ----
// Bu/X  [M][N1] bf16  : 0         (67,108,864 B)  gemm1 out, scan in-place, gemm2 A
// u_bf  [M][DIN] bf16 : 67108864  (16,777,216 B)
// Wp    [N1][DIN] bf16: 83886080  (524,288 B)
// W2    [DOUT][K2]bf16: 84410368  (655,360 B)
// lam   [2*NST] f32   : 85065728
// lamL  [2*NST] f32   : 85069824  (lambda^CHL)
// Ssum  [B][NCH][N1]  : 85073920  (1,048,576 B)
// Pcar  [B][NCH][N1]  : 86122496  (1,048,576 B)
#define OFF_UBF  67108864
#define OFF_WP   83886080
#define OFF_W2   84410368
#define OFF_LAM  85065728
#define OFF_LAML 85069824
#define OFF_SSUM 85073920
#define OFF_PCAR 86122496

__device__ __forceinline__ void gl_lds16(const bf16* g, bf16* l) {
    __builtin_amdgcn_global_load_lds(
        (const __attribute__((address_space(1))) void*)g,
        (__attribute__((address_space(3))) void*)l, 16, 0, 0);
}

// ---- convert u to bf16 ----
__global__ __launch_bounds__(256) void conv_u(const float* __restrict__ u,
                                              bf16* __restrict__ ub) {
    int i = blockIdx.x * 256 + threadIdx.x;     // per 4 floats
    float4 v = ((const float4*)u)[i];
    union { bf16 h[4]; uint2 u2; } p;
    p.h[0] = __float2bfloat16(v.x); p.h[1] = __float2bfloat16(v.y);
    p.h[2] = __float2bfloat16(v.z); p.h[3] = __float2bfloat16(v.w);
    ((uint2*)ub)[i] = p.u2;
}

// ---- pack Wp = gamma*B (bf16), lam, lamL ----
__global__ void pack_w1(const float* __restrict__ nu_log,
                        const float* __restrict__ theta_log,
                        const float* __restrict__ gamma_log,
                        const float* __restrict__ B_real,
                        const float* __restrict__ B_imag,
                        bf16* __restrict__ Wp,
                        float* __restrict__ lam, float* __restrict__ lamL) {
    int c = blockIdx.x;          // 0..1023
    int k = threadIdx.x;         // 0..255
    int n = c & (NST - 1);
    float g = expf(gamma_log[n]);
    const float* src = (c < NST) ? (B_real + (size_t)n * DIN)
                                 : (B_imag + (size_t)n * DIN);
    Wp[(size_t)c * DIN + k] = __float2bfloat16(g * src[k]);
    int idx = c * 256 + k;
    if (idx < NST) {
        float lm = expf(-expf(nu_log[idx]));
        float th = expf(theta_log[idx]);
        float lr = lm * cosf(th), li = lm * sinf(th);
        lam[idx] = lr; lam[NST + idx] = li;
        float ar = lr, ai = li;
#pragma unroll
        for (int q = 0; q < 7; ++q) {        // ^128
            float nr = ar * ar - ai * ai;
            float ni = 2.f * ar * ai;
            ar = nr; ai = ni;
        }
        lamL[idx] = ar; lamL[NST + idx] = ai;
    }
}

// ---- pack W2 = [2*C_real | -2*C_imag | D] bf16 ----
__global__ void pack_w2(const float* __restrict__ C_real,
                        const float* __restrict__ C_imag,
                        const float* __restrict__ Dm,
                        bf16* __restrict__ W2) {
    int idx = blockIdx.x * 256 + threadIdx.x;
    if (idx >= DOUT * K2) return;
    int o = idx / K2;
    int c = idx - o * K2;
    float v;
    if (c < NST)            v =  2.0f * C_real[(size_t)o * NST + c];
    else if (c < 2 * NST)   v = -2.0f * C_imag[(size_t)o * NST + (c - NST)];
    else                    v =  Dm[(size_t)o * DIN + (c - 2 * NST)];
    W2[idx] = __float2bfloat16(v);
}

// ---- GEMM1: Bu[M][N1](bf16) = u_bf[M][DIN] @ Wp[N1][DIN]^T, MFMA ----
__global__ __launch_bounds__(256) void gemm1(const bf16* __restrict__ u,
                                             const bf16* __restrict__ Wp,
                                             bf16* __restrict__ Bu) {
    __shared__ bf16 As[128 * 32];
    __shared__ bf16 Bs[128 * 32];
    const int tid = threadIdx.x;
    const int m0 = blockIdx.x * 128, n0 = blockIdx.y * 128;
    const int lane = tid & 63, w = tid >> 6;
    const int wm = (w >> 1) * 64, wn = (w & 1) * 64;
    const int lr16 = lane & 15, kq = (lane >> 4) * 8;
    const int srow = tid >> 2, scol = (tid & 3) * 8;   // staging: 64 rows/issue

    f32x4 acc[4][4] = {};
    for (int k0 = 0; k0 < DIN; k0 += 32) {
        gl_lds16(u  + (size_t)(m0 + srow) * DIN + k0 + scol,       &As[tid * 8]);
        gl_lds16(u  + (size_t)(m0 + 64 + srow) * DIN + k0 + scol,  &As[2048 + tid * 8]);
        gl_lds16(Wp + (size_t)(n0 + srow) * DIN + k0 + scol,       &Bs[tid * 8]);
        gl_lds16(Wp + (size_t)(n0 + 64 + srow) * DIN + k0 + scol,  &Bs[2048 + tid * 8]);
        __syncthreads();
        bf16x8 af[4], bf_[4];
#pragma unroll
        for (int i = 0; i < 4; ++i)
            af[i] = *(const bf16x8*)(&As[(wm + i * 16 + lr16) * 32 + kq]);
#pragma unroll
        for (int j = 0; j < 4; ++j)
            bf_[j] = *(const bf16x8*)(&Bs[(wn + j * 16 + lr16) * 32 + kq]);
#pragma unroll
        for (int i = 0; i < 4; ++i)
#pragma unroll
            for (int j = 0; j < 4; ++j)
                acc[i][j] = __builtin_amdgcn_mfma_f32_16x16x32_bf16(af[i], bf_[j], acc[i][j], 0, 0, 0);
        __syncthreads();
    }
    const int crow = (lane >> 4) * 4, ccol = lane & 15;
#pragma unroll
    for (int i = 0; i < 4; ++i)
#pragma unroll
        for (int j = 0; j < 4; ++j) {
#pragma unroll
            for (int r = 0; r < 4; ++r) {
                int row = m0 + wm + i * 16 + crow + r;
                int col = n0 + wn + j * 16 + ccol;
                Bu[(size_t)row * N1 + col] = __float2bfloat16(acc[i][j][r]);
            }
        }
}

// ---- scan phase 1: per-(b,n,chunk) local final state ----
__global__ __launch_bounds__(512) void scan1(const bf16* __restrict__ Bu,
                                             const float* __restrict__ lam,
                                             float* __restrict__ Ssum) {
    int n = threadIdx.x;            // 0..511
    int c = blockIdx.x;             // chunk
    int b = blockIdx.y;
    float lr = lam[n], li = lam[NST + n];
    const bf16* base = Bu + ((size_t)b * T_LEN + (size_t)c * CHL) * N1;
    float sr = 0.f, si = 0.f;
    for (int j = 0; j < CHL; ++j) {
        float br = __bfloat162float(base[(size_t)j * N1 + n]);
        float bi = __bfloat162float(base[(size_t)j * N1 + NST + n]);
        float tr = lr * sr - li * si + br;
        float ti = lr * si + li * sr + bi;
        sr = tr; si = ti;
    }
    size_t o = ((size_t)b * NCH + c) * N1 + n;
    Ssum[o] = sr; Ssum[o + NST] = si;
}

// ---- scan phase 2: exclusive scan over chunk summaries ----
__global__ __launch_bounds__(256) void scan2(const float* __restrict__ Ssum,
                                             const float* __restrict__ lamL,
                                             float* __restrict__ Pcar) {
    int idx = blockIdx.x * 256 + threadIdx.x;   // 0..4095
    int b = idx >> 9, n = idx & (NST - 1);
    float Lr = lamL[n], Li = lamL[NST + n];
    float pr = 0.f, pi = 0.f;
    for (int c = 0; c < NCH; ++c) {
        size_t o = ((size_t)b * NCH + c) * N1 + n;
        Pcar[o] = pr; Pcar[o + NST] = pi;
        float sr = Ssum[o], si = Ssum[o + NST];
        float tr = Lr * pr - Li * pi + sr;
        float ti = Lr * pi + Li * pr + si;
        pr = tr; pi = ti;
    }
}

// ---- scan phase 3: apply carry, in-place write x (bf16) ----
__global__ __launch_bounds__(512) void scan3(bf16* __restrict__ Bu,
                                             const float* __restrict__ lam,
                                             const float* __restrict__ Pcar) {
    int n = threadIdx.x;
    int c = blockIdx.x;
    int b = blockIdx.y;
    float lr = lam[n], li = lam[NST + n];
    size_t o = ((size_t)b * NCH + c) * N1 + n;
    float xr = Pcar[o], xi = Pcar[o + NST];
    bf16* base = Bu + ((size_t)b * T_LEN + (size_t)c * CHL) * N1;
    for (int j = 0; j < CHL; ++j) {
        float br = __bfloat162float(base[(size_t)j * N1 + n]);
        float bi = __bfloat162float(base[(size_t)j * N1 + NST + n]);
        float tr = lr * xr - li * xi + br;
        float ti = lr * xi + li * xr + bi;
        xr = tr; xi = ti;
        base[(size_t)j * N1 + n]       = __float2bfloat16(xr);
        base[(size_t)j * N1 + NST + n] = __float2bfloat16(xi);
    }
}

// ---- GEMM2: y[M][DOUT](f32) = [X | u_bf][M][K2] @ W2[DOUT][K2]^T, MFMA ----
__global__ __launch_bounds__(256) void gemm2(const bf16* __restrict__ X,
                                             const bf16* __restrict__ u,
                                             const bf16* __restrict__ W2,
                                             float* __restrict__ y) {
    __shared__ bf16 As[128 * 32];
    __shared__ bf16 Bs[128 * 32];
    const int tid = threadIdx.x;
    const int m0 = blockIdx.x * 128, n0 = blockIdx.y * 128;
    const int lane = tid & 63, w = tid >> 6;
    const int wm = (w >> 1) * 64, wn = (w & 1) * 64;
    const int lr16 = lane & 15, kq = (lane >> 4) * 8;
    const int srow = tid >> 2, scol = (tid & 3) * 8;

    f32x4 acc[4][4] = {};
    for (int k0 = 0; k0 < K2; k0 += 32) {
        const bf16* Asrc; size_t lda; int kc;
        if (k0 < N1) { Asrc = X; lda = N1; kc = k0; }
        else         { Asrc = u; lda = DIN; kc = k0 - N1; }
        gl_lds16(Asrc + (size_t)(m0 + srow) * lda + kc + scol,      &As[tid * 8]);
        gl_lds16(Asrc + (size_t)(m0 + 64 + srow) * lda + kc + scol, &As[2048 + tid * 8]);
        gl_lds16(W2 + (size_t)(n0 + srow) * K2 + k0 + scol,         &Bs[tid * 8]);
        gl_lds16(W2 + (size_t)(n0 + 64 + srow) * K2 + k0 + scol,    &Bs[2048 + tid * 8]);
        __syncthreads();
        bf16x8 af[4], bf_[4];
#pragma unroll
        for (int i = 0; i < 4; ++i)
            af[i] = *(const bf16x8*)(&As[(wm + i * 16 + lr16) * 32 + kq]);
#pragma unroll
        for (int j = 0; j < 4; ++j)
            bf_[j] = *(const bf16x8*)(&Bs[(wn + j * 16 + lr16) * 32 + kq]);
#pragma unroll
        for (int i = 0; i < 4; ++i)
#pragma unroll
            for (int j = 0; j < 4; ++j)
                acc[i][j] = __builtin_amdgcn_mfma_f32_16x16x32_bf16(af[i], bf_[j], acc[i][j], 0, 0, 0);
        __syncthreads();
    }
    const int crow = (lane >> 4) * 4, ccol = lane & 15;
#pragma unroll
    for (int i = 0; i < 4; ++i)
#pragma unroll
        for (int j = 0; j < 4; ++j)
#pragma unroll
            for (int r = 0; r < 4; ++r) {
                int row = m0 + wm + i * 16 + crow + r;
                int col = n0 + wn + j * 16 + ccol;
                y[(size_t)row * DOUT + col] = acc[i][j][r];
            }
}

extern "C" void kernel_launch(void* const* d_in, const int* in_sizes, int n_in,
                              void* d_out, int out_size, void* d_ws, size_t ws_size,
                              hipStream_t stream) {
    const float* u_in      = (const float*)d_in[0];
    const float* nu_log    = (const float*)d_in[1];
    const float* theta_log = (const float*)d_in[2];
    const float* gamma_log = (const float*)d_in[3];
    const float* B_real    = (const float*)d_in[4];
    const float* B_imag    = (const float*)d_in[5];
    const float* C_real    = (const float*)d_in[6];
    const float* C_imag    = (const float*)d_in[7];
    const float* Dm        = (const float*)d_in[8];
    float* y = (float*)d_out;
    char* ws = (char*)d_ws;

    bf16*  Bu   = (bf16*)ws;
    bf16*  u_bf = (bf16*)(ws + OFF_UBF);
    bf16*  Wp   = (bf16*)(ws + OFF_WP);
    bf16*  W2   = (bf16*)(ws + OFF_W2);
    float* lam  = (float*)(ws + OFF_LAM);
    float* lamL = (float*)(ws + OFF_LAML);
    float* Ssum = (float*)(ws + OFF_SSUM);
    float* Pcar = (float*)(ws + OFF_PCAR);

    conv_u<<<(M_ROWS * DIN / 4) / 256, 256, 0, stream>>>(u_in, u_bf);
    pack_w1<<<N1, 256, 0, stream>>>(nu_log, theta_log, gamma_log, B_real, B_imag, Wp, lam, lamL);
    pack_w2<<<(DOUT * K2 + 255) / 256, 256, 0, stream>>>(C_real, C_imag, Dm, W2);
    gemm1<<<dim3(M_ROWS / 128, N1 / 128), 256, 0, stream>>>(u_bf, Wp, Bu);
    scan1<<<dim3(NCH, B_SZ), 512, 0, stream>>>(Bu, lam, Ssum);
    scan2<<<(B_SZ * NST) / 256, 256, 0, stream>>>(Ssum, lamL, Pcar);
    scan3<<<dim3(NCH, B_SZ), 512, 0, stream>>>(Bu, lam, Pcar);
    gemm2<<<dim3(M_ROWS / 128, DOUT / 128), 256, 0, stream>>>(Bu, u_bf, W2, y);
}

// Round 4
// 203.020 us; speedup vs baseline: 4.2598x; 1.0451x over previous
//
#include <hip/hip_runtime.h>
#include <hip/hip_bf16.h>
#include <math.h>

#define B_SZ    8
#define T_LEN   4096
#define DIN     256
#define DOUT    256
#define NST     512
#define M_ROWS  (B_SZ * T_LEN)   // 32768
#define N1      (2 * NST)        // 1024: cols [0,512)=real plane, [512,1024)=imag plane
#define K2      (N1 + DIN)       // 1280
#define CHL     128              // scan chunk length
#define NCH     (T_LEN / CHL)    // 32

typedef __attribute__((ext_vector_type(8))) short bf16x8;
typedef __attribute__((ext_vector_type(4))) float f32x4;
typedef __hip_bfloat16 bf16;

// ws byte offsets (identical to R2)
#define OFF_UBF  67108864
#define OFF_WP   83886080
#define OFF_W2   84410368
#define OFF_LAM  85065728
#define OFF_LAML 85069824
#define OFF_SSUM 85073920
#define OFF_PCAR 86122496

__device__ __forceinline__ void gl_lds16(const bf16* g, bf16* l) {
    __builtin_amdgcn_global_load_lds(
        (const __attribute__((address_space(1))) void*)g,
        (__attribute__((address_space(3))) void*)l, 16, 0, 0);
}

// ---- prep: conv_u (blocks 0..8191) + pack_w1 (8192..9215) + pack_w2 (rest) ----
// Split-plane semantics, byte-identical to R2's three kernels.
__global__ __launch_bounds__(256) void prep(const float* __restrict__ u,
        const float* __restrict__ nu_log, const float* __restrict__ theta_log,
        const float* __restrict__ gamma_log,
        const float* __restrict__ B_real, const float* __restrict__ B_imag,
        const float* __restrict__ C_real, const float* __restrict__ C_imag,
        const float* __restrict__ Dm,
        bf16* __restrict__ ub, bf16* __restrict__ Wp, bf16* __restrict__ W2,
        float* __restrict__ lam, float* __restrict__ lamL) {
    int bid = blockIdx.x, tid = threadIdx.x;
    if (bid < 8192) {                       // u -> bf16
        int i = bid * 256 + tid;
        float4 v = ((const float4*)u)[i];
        union { bf16 h[4]; uint2 u2; } p;
        p.h[0] = __float2bfloat16(v.x); p.h[1] = __float2bfloat16(v.y);
        p.h[2] = __float2bfloat16(v.z); p.h[3] = __float2bfloat16(v.w);
        ((uint2*)ub)[i] = p.u2;
    } else if (bid < 9216) {                // Wp (split planes) + lam/lamL
        int c = bid - 8192;                 // 0..1023
        int n = c & (NST - 1);
        float g = expf(gamma_log[n]);
        const float* src = (c < NST) ? (B_real + (size_t)n * DIN)
                                     : (B_imag + (size_t)n * DIN);
        Wp[(size_t)c * DIN + tid] = __float2bfloat16(g * src[tid]);
        int idx = c * 256 + tid;
        if (idx < NST) {
            float lm = expf(-expf(nu_log[idx]));
            float th = expf(theta_log[idx]);
            float lr = lm * cosf(th), li = lm * sinf(th);
            lam[idx] = lr; lam[NST + idx] = li;
            float ar = lr, ai = li;
#pragma unroll
            for (int q = 0; q < 7; ++q) {   // lambda^128
                float nr = ar * ar - ai * ai;
                float ni = 2.f * ar * ai;
                ar = nr; ai = ni;
            }
            lamL[idx] = ar; lamL[NST + idx] = ai;
        }
    } else {                                // W2 = [2Cr | -2Ci | D] split
        int idx = (bid - 9216) * 256 + tid;
        if (idx < DOUT * K2) {
            int o = idx / K2, c = idx - o * K2;
            float v;
            if (c < NST)            v =  2.0f * C_real[(size_t)o * NST + c];
            else if (c < 2 * NST)   v = -2.0f * C_imag[(size_t)o * NST + (c - NST)];
            else                    v =  Dm[(size_t)o * DIN + (c - 2 * NST)];
            W2[idx] = __float2bfloat16(v);
        }
    }
}

// ---- GEMM1: Bu[M][N1](bf16) = u_bf @ Wp^T (R2 verbatim) ----
__global__ __launch_bounds__(256) void gemm1(const bf16* __restrict__ u,
                                             const bf16* __restrict__ Wp,
                                             bf16* __restrict__ Bu) {
    __shared__ bf16 As[128 * 32];
    __shared__ bf16 Bs[128 * 32];
    const int tid = threadIdx.x;
    const int m0 = blockIdx.x * 128, n0 = blockIdx.y * 128;
    const int lane = tid & 63, w = tid >> 6;
    const int wm = (w >> 1) * 64, wn = (w & 1) * 64;
    const int lr16 = lane & 15, kq = (lane >> 4) * 8;
    const int srow = tid >> 2, scol = (tid & 3) * 8;

    f32x4 acc[4][4] = {};
    for (int k0 = 0; k0 < DIN; k0 += 32) {
        gl_lds16(u  + (size_t)(m0 + srow) * DIN + k0 + scol,       &As[tid * 8]);
        gl_lds16(u  + (size_t)(m0 + 64 + srow) * DIN + k0 + scol,  &As[2048 + tid * 8]);
        gl_lds16(Wp + (size_t)(n0 + srow) * DIN + k0 + scol,       &Bs[tid * 8]);
        gl_lds16(Wp + (size_t)(n0 + 64 + srow) * DIN + k0 + scol,  &Bs[2048 + tid * 8]);
        __syncthreads();
        bf16x8 af[4], bfr[4];
#pragma unroll
        for (int i = 0; i < 4; ++i)
            af[i] = *(const bf16x8*)(&As[(wm + i * 16 + lr16) * 32 + kq]);
#pragma unroll
        for (int j = 0; j < 4; ++j)
            bfr[j] = *(const bf16x8*)(&Bs[(wn + j * 16 + lr16) * 32 + kq]);
#pragma unroll
        for (int i = 0; i < 4; ++i)
#pragma unroll
            for (int j = 0; j < 4; ++j)
                acc[i][j] = __builtin_amdgcn_mfma_f32_16x16x32_bf16(af[i], bfr[j], acc[i][j], 0, 0, 0);
        __syncthreads();
    }
    const int crow = (lane >> 4) * 4, ccol = lane & 15;
#pragma unroll
    for (int i = 0; i < 4; ++i)
#pragma unroll
        for (int j = 0; j < 4; ++j)
#pragma unroll
            for (int r = 0; r < 4; ++r) {
                int row = m0 + wm + i * 16 + crow + r;
                int col = n0 + wn + j * 16 + ccol;
                Bu[(size_t)row * N1 + col] = __float2bfloat16(acc[i][j][r]);
            }
}

// ---- scan phase 1 (R2 verbatim) ----
__global__ __launch_bounds__(512) void scan1(const bf16* __restrict__ Bu,
                                             const float* __restrict__ lam,
                                             float* __restrict__ Ssum) {
    int n = threadIdx.x;
    int c = blockIdx.x;
    int b = blockIdx.y;
    float lr = lam[n], li = lam[NST + n];
    const bf16* base = Bu + ((size_t)b * T_LEN + (size_t)c * CHL) * N1;
    float sr = 0.f, si = 0.f;
    for (int j = 0; j < CHL; ++j) {
        float br = __bfloat162float(base[(size_t)j * N1 + n]);
        float bi = __bfloat162float(base[(size_t)j * N1 + NST + n]);
        float tr = lr * sr - li * si + br;
        float ti = lr * si + li * sr + bi;
        sr = tr; si = ti;
    }
    size_t o = ((size_t)b * NCH + c) * N1 + n;
    Ssum[o] = sr; Ssum[o + NST] = si;
}

// ---- scan phase 2 (R2 verbatim) ----
__global__ __launch_bounds__(256) void scan2(const float* __restrict__ Ssum,
                                             const float* __restrict__ lamL,
                                             float* __restrict__ Pcar) {
    int idx = blockIdx.x * 256 + threadIdx.x;
    int b = idx >> 9, n = idx & (NST - 1);
    float Lr = lamL[n], Li = lamL[NST + n];
    float pr = 0.f, pi = 0.f;
    for (int c = 0; c < NCH; ++c) {
        size_t o = ((size_t)b * NCH + c) * N1 + n;
        Pcar[o] = pr; Pcar[o + NST] = pi;
        float sr = Ssum[o], si = Ssum[o + NST];
        float tr = Lr * pr - Li * pi + sr;
        float ti = Lr * pi + Li * pr + si;
        pr = tr; pi = ti;
    }
}

// ---- scan phase 3 (R2 verbatim) ----
__global__ __launch_bounds__(512) void scan3(bf16* __restrict__ Bu,
                                             const float* __restrict__ lam,
                                             const float* __restrict__ Pcar) {
    int n = threadIdx.x, c = blockIdx.x, b = blockIdx.y;
    float lr = lam[n], li = lam[NST + n];
    size_t o = ((size_t)b * NCH + c) * N1 + n;
    float xr = Pcar[o], xi = Pcar[o + NST];
    bf16* base = Bu + ((size_t)b * T_LEN + (size_t)c * CHL) * N1;
    for (int j = 0; j < CHL; ++j) {
        float br = __bfloat162float(base[(size_t)j * N1 + n]);
        float bi = __bfloat162float(base[(size_t)j * N1 + NST + n]);
        float tr = lr * xr - li * xi + br;
        float ti = lr * xi + li * xr + bi;
        xr = tr; xi = ti;
        base[(size_t)j * N1 + n]       = __float2bfloat16(xr);
        base[(size_t)j * N1 + NST + n] = __float2bfloat16(xi);
    }
}

// ---- GEMM2: y = [X | u_bf] @ W2^T, 512 threads / 8 waves ----
__global__ __launch_bounds__(512) void gemm2(const bf16* __restrict__ X,
                                             const bf16* __restrict__ u,
                                             const bf16* __restrict__ W2,
                                             float* __restrict__ y) {
    __shared__ bf16 As[128 * 32];
    __shared__ bf16 Bs[128 * 32];
    const int tid = threadIdx.x;
    const int m0 = blockIdx.x * 128, n0 = blockIdx.y * 128;
    const int lane = tid & 63, w = tid >> 6;
    const int wm = (w >> 2) * 64, wn = (w & 3) * 32;   // 2x4 wave grid, 64x32 each
    const int lr16 = lane & 15, kq = (lane >> 4) * 8;
    const int srow = tid >> 2, scol = (tid & 3) * 8;   // 512 threads cover 128 rows

    f32x4 acc[4][2] = {};
    for (int k0 = 0; k0 < K2; k0 += 32) {
        const bf16* Asrc; size_t lda; int kc;
        if (k0 < N1) { Asrc = X; lda = N1;  kc = k0; }
        else         { Asrc = u; lda = DIN; kc = k0 - N1; }
        gl_lds16(Asrc + (size_t)(m0 + srow) * lda + kc + scol, &As[tid * 8]);
        gl_lds16(W2 + (size_t)(n0 + srow) * K2 + k0 + scol,    &Bs[tid * 8]);
        __syncthreads();
        bf16x8 af[4], bfr[2];
#pragma unroll
        for (int i = 0; i < 4; ++i)
            af[i] = *(const bf16x8*)(&As[(wm + i * 16 + lr16) * 32 + kq]);
#pragma unroll
        for (int j = 0; j < 2; ++j)
            bfr[j] = *(const bf16x8*)(&Bs[(wn + j * 16 + lr16) * 32 + kq]);
#pragma unroll
        for (int i = 0; i < 4; ++i)
#pragma unroll
            for (int j = 0; j < 2; ++j)
                acc[i][j] = __builtin_amdgcn_mfma_f32_16x16x32_bf16(af[i], bfr[j], acc[i][j], 0, 0, 0);
        __syncthreads();
    }
    const int crow = (lane >> 4) * 4, ccol = lane & 15;
#pragma unroll
    for (int i = 0; i < 4; ++i)
#pragma unroll
        for (int j = 0; j < 2; ++j)
#pragma unroll
            for (int r = 0; r < 4; ++r)
                y[(size_t)(m0 + wm + i * 16 + crow + r) * DOUT + n0 + wn + j * 16 + ccol] = acc[i][j][r];
}

extern "C" void kernel_launch(void* const* d_in, const int* in_sizes, int n_in,
                              void* d_out, int out_size, void* d_ws, size_t ws_size,
                              hipStream_t stream) {
    const float* u_in      = (const float*)d_in[0];
    const float* nu_log    = (const float*)d_in[1];
    const float* theta_log = (const float*)d_in[2];
    const float* gamma_log = (const float*)d_in[3];
    const float* B_real    = (const float*)d_in[4];
    const float* B_imag    = (const float*)d_in[5];
    const float* C_real    = (const float*)d_in[6];
    const float* C_imag    = (const float*)d_in[7];
    const float* Dm        = (const float*)d_in[8];
    float* y = (float*)d_out;
    char* ws = (char*)d_ws;

    bf16*  Bu   = (bf16*)ws;
    bf16*  u_bf = (bf16*)(ws + OFF_UBF);
    bf16*  Wp   = (bf16*)(ws + OFF_WP);
    bf16*  W2   = (bf16*)(ws + OFF_W2);
    float* lam  = (float*)(ws + OFF_LAM);
    float* lamL = (float*)(ws + OFF_LAML);
    float* Ssum = (float*)(ws + OFF_SSUM);
    float* Pcar = (float*)(ws + OFF_PCAR);

    prep<<<10496, 256, 0, stream>>>(u_in, nu_log, theta_log, gamma_log,
                                    B_real, B_imag, C_real, C_imag, Dm,
                                    u_bf, Wp, W2, lam, lamL);
    gemm1<<<dim3(M_ROWS / 128, N1 / 128), 256, 0, stream>>>(u_bf, Wp, Bu);
    scan1<<<dim3(NCH, B_SZ), 512, 0, stream>>>(Bu, lam, Ssum);
    scan2<<<(B_SZ * NST) / 256, 256, 0, stream>>>(Ssum, lamL, Pcar);
    scan3<<<dim3(NCH, B_SZ), 512, 0, stream>>>(Bu, lam, Pcar);
    gemm2<<<dim3(M_ROWS / 128, DOUT / 128), 512, 0, stream>>>(Bu, u_bf, W2, y);
}

// Round 7
// 198.974 us; speedup vs baseline: 4.3464x; 1.0203x over previous
//
#include <hip/hip_runtime.h>
#include <hip/hip_bf16.h>
#include <math.h>

#define B_SZ    8
#define T_LEN   4096
#define DIN     256
#define DOUT    256
#define NST     512
#define M_ROWS  (B_SZ * T_LEN)   // 32768
#define N1      (2 * NST)        // 1024: cols [0,512)=real plane, [512,1024)=imag plane
#define K2      (N1 + DIN)       // 1280
#define CHL     128              // scan chunk length
#define NCH     (T_LEN / CHL)    // 32

typedef __attribute__((ext_vector_type(8))) short bf16x8;
typedef __attribute__((ext_vector_type(4))) float f32x4;
typedef __hip_bfloat16 bf16;

// ws byte offsets (identical to R2/R4; Pcar slot now unused)
#define OFF_UBF  67108864
#define OFF_WP   83886080
#define OFF_W2   84410368
#define OFF_LAM  85065728
#define OFF_LAML 85069824
#define OFF_SSUM 85073920

__device__ __forceinline__ void gl_lds16(const bf16* g, bf16* l) {
    __builtin_amdgcn_global_load_lds(
        (const __attribute__((address_space(1))) void*)g,
        (__attribute__((address_space(3))) void*)l, 16, 0, 0);
}

// ---- prep (R4 verbatim): conv_u + pack_w1 + pack_w2, split-plane ----
__global__ __launch_bounds__(256) void prep(const float* __restrict__ u,
        const float* __restrict__ nu_log, const float* __restrict__ theta_log,
        const float* __restrict__ gamma_log,
        const float* __restrict__ B_real, const float* __restrict__ B_imag,
        const float* __restrict__ C_real, const float* __restrict__ C_imag,
        const float* __restrict__ Dm,
        bf16* __restrict__ ub, bf16* __restrict__ Wp, bf16* __restrict__ W2,
        float* __restrict__ lam, float* __restrict__ lamL) {
    int bid = blockIdx.x, tid = threadIdx.x;
    if (bid < 8192) {                       // u -> bf16
        int i = bid * 256 + tid;
        float4 v = ((const float4*)u)[i];
        union { bf16 h[4]; uint2 u2; } p;
        p.h[0] = __float2bfloat16(v.x); p.h[1] = __float2bfloat16(v.y);
        p.h[2] = __float2bfloat16(v.z); p.h[3] = __float2bfloat16(v.w);
        ((uint2*)ub)[i] = p.u2;
    } else if (bid < 9216) {                // Wp (split planes) + lam/lamL
        int c = bid - 8192;                 // 0..1023
        int n = c & (NST - 1);
        float g = expf(gamma_log[n]);
        const float* src = (c < NST) ? (B_real + (size_t)n * DIN)
                                     : (B_imag + (size_t)n * DIN);
        Wp[(size_t)c * DIN + tid] = __float2bfloat16(g * src[tid]);
        int idx = c * 256 + tid;
        if (idx < NST) {
            float lm = expf(-expf(nu_log[idx]));
            float th = expf(theta_log[idx]);
            float lr = lm * cosf(th), li = lm * sinf(th);
            lam[idx] = lr; lam[NST + idx] = li;
            float ar = lr, ai = li;
#pragma unroll
            for (int q = 0; q < 7; ++q) {   // lambda^128
                float nr = ar * ar - ai * ai;
                float ni = 2.f * ar * ai;
                ar = nr; ai = ni;
            }
            lamL[idx] = ar; lamL[NST + idx] = ai;
        }
    } else {                                // W2 = [2Cr | -2Ci | D] split
        int idx = (bid - 9216) * 256 + tid;
        if (idx < DOUT * K2) {
            int o = idx / K2, c = idx - o * K2;
            float v;
            if (c < NST)            v =  2.0f * C_real[(size_t)o * NST + c];
            else if (c < 2 * NST)   v = -2.0f * C_imag[(size_t)o * NST + (c - NST)];
            else                    v =  Dm[(size_t)o * DIN + (c - 2 * NST)];
            W2[idx] = __float2bfloat16(v);
        }
    }
}

// ---- GEMM1 (R4 dataflow) with LDS-packed coalesced Bu stores ----
// C-tile staged to padded LDS (128x136 bf16), then written as 16B uint4:
// 64 lanes cover 4 full 256B rows per store instruction.
__global__ __launch_bounds__(256) void gemm1(const bf16* __restrict__ u,
                                             const bf16* __restrict__ Wp,
                                             bf16* __restrict__ Bu) {
    __shared__ bf16 As[128 * 32];
    __shared__ bf16 Bs[128 * 32];
    __shared__ bf16 Cs[128 * 136];       // +8 pad: spreads 2B-scatter banks
    const int tid = threadIdx.x;
    const int m0 = blockIdx.x * 128, n0 = blockIdx.y * 128;
    const int lane = tid & 63, w = tid >> 6;
    const int wm = (w >> 1) * 64, wn = (w & 1) * 64;
    const int lr16 = lane & 15, kq = (lane >> 4) * 8;
    const int srow = tid >> 2, scol = (tid & 3) * 8;

    f32x4 acc[4][4] = {};
    for (int k0 = 0; k0 < DIN; k0 += 32) {
        gl_lds16(u  + (size_t)(m0 + srow) * DIN + k0 + scol,       &As[tid * 8]);
        gl_lds16(u  + (size_t)(m0 + 64 + srow) * DIN + k0 + scol,  &As[2048 + tid * 8]);
        gl_lds16(Wp + (size_t)(n0 + srow) * DIN + k0 + scol,       &Bs[tid * 8]);
        gl_lds16(Wp + (size_t)(n0 + 64 + srow) * DIN + k0 + scol,  &Bs[2048 + tid * 8]);
        __syncthreads();
        bf16x8 af[4], bfr[4];
#pragma unroll
        for (int i = 0; i < 4; ++i)
            af[i] = *(const bf16x8*)(&As[(wm + i * 16 + lr16) * 32 + kq]);
#pragma unroll
        for (int j = 0; j < 4; ++j)
            bfr[j] = *(const bf16x8*)(&Bs[(wn + j * 16 + lr16) * 32 + kq]);
#pragma unroll
        for (int i = 0; i < 4; ++i)
#pragma unroll
            for (int j = 0; j < 4; ++j)
                acc[i][j] = __builtin_amdgcn_mfma_f32_16x16x32_bf16(af[i], bfr[j], acc[i][j], 0, 0, 0);
        __syncthreads();
    }
    const int crow = (lane >> 4) * 4, ccol = lane & 15;
#pragma unroll
    for (int i = 0; i < 4; ++i)
#pragma unroll
        for (int j = 0; j < 4; ++j)
#pragma unroll
            for (int r = 0; r < 4; ++r)
                Cs[(wm + i * 16 + crow + r) * 136 + wn + j * 16 + ccol] =
                    __float2bfloat16(acc[i][j][r]);
    __syncthreads();
#pragma unroll
    for (int p = 0; p < 8; ++p) {
        int row = p * 16 + (tid >> 4);
        int colg = (tid & 15) * 8;
        *(uint4*)(&Bu[(size_t)(m0 + row) * N1 + n0 + colg]) =
            *(const uint4*)(&Cs[row * 136 + colg]);
    }
}

// ---- scan phase 1 (R4 verbatim): per-(b,n,chunk) final state ----
__global__ __launch_bounds__(512) void scan1(const bf16* __restrict__ Bu,
                                             const float* __restrict__ lam,
                                             float* __restrict__ Ssum) {
    int n = threadIdx.x;
    int c = blockIdx.x;
    int b = blockIdx.y;
    float lr = lam[n], li = lam[NST + n];
    const bf16* base = Bu + ((size_t)b * T_LEN + (size_t)c * CHL) * N1;
    float sr = 0.f, si = 0.f;
    for (int j = 0; j < CHL; ++j) {
        float br = __bfloat162float(base[(size_t)j * N1 + n]);
        float bi = __bfloat162float(base[(size_t)j * N1 + NST + n]);
        float tr = lr * sr - li * si + br;
        float ti = lr * si + li * sr + bi;
        sr = tr; si = ti;
    }
    size_t o = ((size_t)b * NCH + c) * N1 + n;
    Ssum[o] = sr; Ssum[o + NST] = si;
}

// ---- scan phase 3 with INLINE carry (replaces scan2+Pcar) ----
// Carry recomputed per block: p = L*p + S_c' over c' < c — bitwise identical
// to the old scan2 exclusive scan. Ssum is 1 MB → L2-resident, ~free.
__global__ __launch_bounds__(512) void scan3(bf16* __restrict__ Bu,
                                             const float* __restrict__ lam,
                                             const float* __restrict__ lamL,
                                             const float* __restrict__ Ssum) {
    int n = threadIdx.x, c = blockIdx.x, b = blockIdx.y;
    float lr = lam[n], li = lam[NST + n];
    float Lr = lamL[n], Li = lamL[NST + n];
    float pr = 0.f, pi = 0.f;
    for (int cp = 0; cp < c; ++cp) {
        size_t o = ((size_t)b * NCH + cp) * N1 + n;
        float sr = Ssum[o], si = Ssum[o + NST];
        float tr = Lr * pr - Li * pi + sr;
        float ti = Lr * pi + Li * pr + si;
        pr = tr; pi = ti;
    }
    float xr = pr, xi = pi;
    bf16* base = Bu + ((size_t)b * T_LEN + (size_t)c * CHL) * N1;
    for (int j = 0; j < CHL; ++j) {
        float br = __bfloat162float(base[(size_t)j * N1 + n]);
        float bi = __bfloat162float(base[(size_t)j * N1 + NST + n]);
        float tr = lr * xr - li * xi + br;
        float ti = lr * xi + li * xr + bi;
        xr = tr; xi = ti;
        base[(size_t)j * N1 + n]       = __float2bfloat16(xr);
        base[(size_t)j * N1 + NST + n] = __float2bfloat16(xi);
    }
}

// ---- GEMM2 (R4 verbatim): y = [X | u_bf] @ W2^T, 512 threads / 8 waves ----
__global__ __launch_bounds__(512) void gemm2(const bf16* __restrict__ X,
                                             const bf16* __restrict__ u,
                                             const bf16* __restrict__ W2,
                                             float* __restrict__ y) {
    __shared__ bf16 As[128 * 32];
    __shared__ bf16 Bs[128 * 32];
    const int tid = threadIdx.x;
    const int m0 = blockIdx.x * 128, n0 = blockIdx.y * 128;
    const int lane = tid & 63, w = tid >> 6;
    const int wm = (w >> 2) * 64, wn = (w & 3) * 32;   // 2x4 wave grid, 64x32 each
    const int lr16 = lane & 15, kq = (lane >> 4) * 8;
    const int srow = tid >> 2, scol = (tid & 3) * 8;   // 512 threads cover 128 rows

    f32x4 acc[4][2] = {};
    for (int k0 = 0; k0 < K2; k0 += 32) {
        const bf16* Asrc; size_t lda; int kc;
        if (k0 < N1) { Asrc = X; lda = N1;  kc = k0; }
        else         { Asrc = u; lda = DIN; kc = k0 - N1; }
        gl_lds16(Asrc + (size_t)(m0 + srow) * lda + kc + scol, &As[tid * 8]);
        gl_lds16(W2 + (size_t)(n0 + srow) * K2 + k0 + scol,    &Bs[tid * 8]);
        __syncthreads();
        bf16x8 af[4], bfr[2];
#pragma unroll
        for (int i = 0; i < 4; ++i)
            af[i] = *(const bf16x8*)(&As[(wm + i * 16 + lr16) * 32 + kq]);
#pragma unroll
        for (int j = 0; j < 2; ++j)
            bfr[j] = *(const bf16x8*)(&Bs[(wn + j * 16 + lr16) * 32 + kq]);
#pragma unroll
        for (int i = 0; i < 4; ++i)
#pragma unroll
            for (int j = 0; j < 2; ++j)
                acc[i][j] = __builtin_amdgcn_mfma_f32_16x16x32_bf16(af[i], bfr[j], acc[i][j], 0, 0, 0);
        __syncthreads();
    }
    const int crow = (lane >> 4) * 4, ccol = lane & 15;
#pragma unroll
    for (int i = 0; i < 4; ++i)
#pragma unroll
        for (int j = 0; j < 2; ++j)
#pragma unroll
            for (int r = 0; r < 4; ++r)
                y[(size_t)(m0 + wm + i * 16 + crow + r) * DOUT + n0 + wn + j * 16 + ccol] = acc[i][j][r];
}

extern "C" void kernel_launch(void* const* d_in, const int* in_sizes, int n_in,
                              void* d_out, int out_size, void* d_ws, size_t ws_size,
                              hipStream_t stream) {
    const float* u_in      = (const float*)d_in[0];
    const float* nu_log    = (const float*)d_in[1];
    const float* theta_log = (const float*)d_in[2];
    const float* gamma_log = (const float*)d_in[3];
    const float* B_real    = (const float*)d_in[4];
    const float* B_imag    = (const float*)d_in[5];
    const float* C_real    = (const float*)d_in[6];
    const float* C_imag    = (const float*)d_in[7];
    const float* Dm        = (const float*)d_in[8];
    float* y = (float*)d_out;
    char* ws = (char*)d_ws;

    bf16*  Bu   = (bf16*)ws;
    bf16*  u_bf = (bf16*)(ws + OFF_UBF);
    bf16*  Wp   = (bf16*)(ws + OFF_WP);
    bf16*  W2   = (bf16*)(ws + OFF_W2);
    float* lam  = (float*)(ws + OFF_LAM);
    float* lamL = (float*)(ws + OFF_LAML);
    float* Ssum = (float*)(ws + OFF_SSUM);

    prep<<<10496, 256, 0, stream>>>(u_in, nu_log, theta_log, gamma_log,
                                    B_real, B_imag, C_real, C_imag, Dm,
                                    u_bf, Wp, W2, lam, lamL);
    gemm1<<<dim3(M_ROWS / 128, N1 / 128), 256, 0, stream>>>(u_bf, Wp, Bu);
    scan1<<<dim3(NCH, B_SZ), 512, 0, stream>>>(Bu, lam, Ssum);
    scan3<<<dim3(NCH, B_SZ), 512, 0, stream>>>(Bu, lam, lamL, Ssum);
    gemm2<<<dim3(M_ROWS / 128, DOUT / 128), 512, 0, stream>>>(Bu, u_bf, W2, y);
}